// Round 1
// baseline (1502.475 us; speedup 1.0000x reference)
//
#include <hip/hip_runtime.h>
#include <hip/hip_bf16.h>
#include <math.h>

#define D_IN   768
#define D_SAE  12288
#define T_LEN  64
#define K_TOP  64
#define B_SZ   32
#define NROWS  (B_SZ * T_LEN)   // 2048

// ---------- helpers ----------
__device__ __forceinline__ unsigned int f2key(float f) {
  unsigned int u = __float_as_uint(f);
  return (u & 0x80000000u) ? ~u : (u | 0x80000000u);
}

// ---------- kernel 0: init output (loss slot + z_last region) ----------
__global__ void sae_init_out(float* __restrict__ d_out) {
  int i = blockIdx.x * blockDim.x + threadIdx.x;
  if (i == 0) d_out[0] = 0.0f;
  if (i < B_SZ * D_SAE) d_out[1 + (size_t)NROWS * D_IN + i] = 0.0f;
}

// ---------- kernel 1: encoder GEMM, fp32 vector ----------
// C[m][n] = sum_k A[m][k]*B[k][n] + bias[n];  M=2048, N=12288, K=768
#define BM 128
#define BN 128
#define BK 16
__global__ __launch_bounds__(256) void sae_gemm_enc(
    const float* __restrict__ A, const float* __restrict__ Bm,
    const float* __restrict__ bias, float* __restrict__ C) {
  __shared__ float As[BK][BM];   // transposed A tile
  __shared__ float Bs[BK][BN];
  const int tid = threadIdx.x;
  const int bm = blockIdx.y * BM;
  const int bn = blockIdx.x * BN;
  const int tr  = (tid >> 4) << 3;        // 0..120, 8 contiguous rows
  const int tcq = (tid & 15) << 2;        // 0..60, cols tcq..+3 and 64+tcq..+3

  float acc[8][8];
#pragma unroll
  for (int i = 0; i < 8; ++i)
#pragma unroll
    for (int j = 0; j < 8; ++j) acc[i][j] = 0.0f;

  for (int k0 = 0; k0 < D_IN; k0 += BK) {
    __syncthreads();
#pragma unroll
    for (int l = 0; l < 2; ++l) {
      int idx = tid + (l << 8);           // 0..511
      int r = idx >> 2, c4 = idx & 3;
      const float4 av = *(const float4*)(A + (size_t)(bm + r) * D_IN + k0 + (c4 << 2));
      As[(c4 << 2) + 0][r] = av.x;
      As[(c4 << 2) + 1][r] = av.y;
      As[(c4 << 2) + 2][r] = av.z;
      As[(c4 << 2) + 3][r] = av.w;
      int rb = idx >> 5, cb = idx & 31;
      *(float4*)(&Bs[rb][cb << 2]) =
          *(const float4*)(Bm + (size_t)(k0 + rb) * D_SAE + bn + (cb << 2));
    }
    __syncthreads();
#pragma unroll
    for (int kk = 0; kk < BK; ++kk) {
      float a[8], b[8];
      *(float4*)&a[0] = *(const float4*)&As[kk][tr];
      *(float4*)&a[4] = *(const float4*)&As[kk][tr + 4];
      *(float4*)&b[0] = *(const float4*)&Bs[kk][tcq];
      *(float4*)&b[4] = *(const float4*)&Bs[kk][tcq + 64];
#pragma unroll
      for (int i = 0; i < 8; ++i)
#pragma unroll
        for (int j = 0; j < 8; ++j)
          acc[i][j] = fmaf(a[i], b[j], acc[i][j]);
    }
  }
  // epilogue with bias
#pragma unroll
  for (int i = 0; i < 8; ++i) {
    size_t base = (size_t)(bm + tr + i) * D_SAE + bn;
    float4 o0, o1;
    o0.x = acc[i][0] + bias[bn + tcq + 0];
    o0.y = acc[i][1] + bias[bn + tcq + 1];
    o0.z = acc[i][2] + bias[bn + tcq + 2];
    o0.w = acc[i][3] + bias[bn + tcq + 3];
    o1.x = acc[i][4] + bias[bn + 64 + tcq + 0];
    o1.y = acc[i][5] + bias[bn + 64 + tcq + 1];
    o1.z = acc[i][6] + bias[bn + 64 + tcq + 2];
    o1.w = acc[i][7] + bias[bn + 64 + tcq + 3];
    *(float4*)(C + base + tcq)      = o0;
    *(float4*)(C + base + 64 + tcq) = o1;
  }
}

// ---------- kernel 2: exact top-128 per row (radix select on sortable keys) ----------
__global__ __launch_bounds__(256) void sae_top128(
    const float* __restrict__ pre, int* __restrict__ t128i, float* __restrict__ t128v) {
  const int row = blockIdx.x;
  const int tid = threadIdx.x;
  __shared__ unsigned int keys[D_SAE];     // 48 KB
  __shared__ int hist[256];
  __shared__ int scn[256];
  __shared__ int sb, srem, scnt, scnt2;
  const float* p = pre + (size_t)row * D_SAE;
  for (int i = tid; i < D_SAE; i += 256) keys[i] = f2key(p[i]);

  const unsigned int PMASK[4] = {0u, 0xFF000000u, 0xFFFF0000u, 0xFFFFFF00u};
  unsigned int pacc = 0;      // accumulated threshold prefix (aligned in place)
  int remaining = 128;

  for (int round = 0; round < 4; ++round) {
    const int shift = 24 - 8 * round;
    hist[tid] = 0;
    __syncthreads();
    unsigned int pm = PMASK[round];
    for (int i = tid; i < D_SAE; i += 256) {
      unsigned int k = keys[i];
      if ((k & pm) == pacc) atomicAdd(&hist[(k >> shift) & 255], 1);
    }
    __syncthreads();
    // reverse inclusive scan: scn[b] = count(byte >= b)
    scn[tid] = hist[tid];
    __syncthreads();
    for (int d = 1; d < 256; d <<= 1) {
      int nv = scn[tid] + ((tid + d < 256) ? scn[tid + d] : 0);
      __syncthreads();
      scn[tid] = nv;
      __syncthreads();
    }
    int cum = scn[tid];
    int nxt = (tid < 255) ? scn[tid + 1] : 0;
    if (cum >= remaining && nxt < remaining) { sb = tid; srem = remaining - nxt; }
    __syncthreads();
    pacc |= ((unsigned int)sb) << shift;
    remaining = srem;
    __syncthreads();
  }
  // pacc = key of the 128th largest; remaining = # equal keys to take
  if (tid == 0) { scnt = 0; scnt2 = 0; }
  __syncthreads();
  const int ngt = 128 - remaining;
  for (int i = tid; i < D_SAE; i += 256) {
    unsigned int k = keys[i];
    if (k > pacc) {
      int pos = atomicAdd(&scnt, 1);
      t128i[row * 128 + pos] = i;
      t128v[row * 128 + pos] = p[i];
    } else if (k == pacc) {
      int pos = atomicAdd(&scnt2, 1);
      if (pos < remaining) {
        t128i[row * 128 + ngt + pos] = i;
        t128v[row * 128 + ngt + pos] = p[i];
      }
    }
  }
}

// ---------- kernel 3: recurrence — one wave per batch chain ----------
__global__ __launch_bounds__(64) void sae_recur(
    const float* __restrict__ pre, const int* __restrict__ t128i,
    const float* __restrict__ t128v, const float* __restrict__ gate_raw,
    int* __restrict__ zi, float* __restrict__ zv) {
  const int b = blockIdx.x;
  const int lane = threadIdx.x;
  __shared__ int   ci[192];
  __shared__ float cv[192];
  __shared__ unsigned long long ckey[192];
  __shared__ int   nzi[64];
  __shared__ float nzv[64];

  int   zidx = 0;
  float zval = 0.0f;   // empty previous state at t=0

  for (int t = 0; t < T_LEN; ++t) {
    const int row = b * T_LEN + t;
    int   ri0 = t128i[row * 128 + lane];
    float rv0 = t128v[row * 128 + lane];
    int   ri1 = t128i[row * 128 + 64 + lane];
    float rv1 = t128v[row * 128 + 64 + lane];

    bool active = (zval > 0.0f);
    float gz = 0.0f;
    if (active) {
      float gr = gate_raw[zidx];
      gz = zval * (1.0f / (1.0f + __expf(-gr)));
    }
    bool matched = false;
    for (int j = 0; j < 64; ++j) {
      int actj = __shfl((int)active, j);
      if (!actj) continue;
      int   pj  = __shfl(zidx, j);
      float gzj = __shfl(gz, j);
      bool m0 = (ri0 == pj);
      bool m1 = (ri1 == pj);
      if (m0) rv0 += gzj;
      if (m1) rv1 += gzj;
      if (__any(m0 || m1) && lane == j) matched = true;
    }
    // candidate slots: 0..127 = (boosted) top-128, 128..191 = extras/pads
    ci[lane]       = ri0;  cv[lane]       = rv0;
    ci[64 + lane]  = ri1;  cv[64 + lane]  = rv1;
    ci[128 + lane] = D_SAE + lane;  cv[128 + lane] = -INFINITY;
    __syncthreads();
    bool extra = active && !matched;
    unsigned long long em = __ballot(extra);
    if (extra) {
      int pos = __popcll(em & ((1ull << lane) - 1ull));
      ci[128 + pos] = zidx;
      cv[128 + pos] = pre[(size_t)row * D_SAE + zidx] + gz;
    }
    __syncthreads();
    int   xi2 = ci[128 + lane];
    float xv2 = cv[128 + lane];
    unsigned long long k0 =
        (((unsigned long long)f2key(rv0)) << 14) | (unsigned)(16383 - ri0);
    unsigned long long k1 =
        (((unsigned long long)f2key(rv1)) << 14) | (unsigned)(16383 - ri1);
    unsigned long long k2 =
        (((unsigned long long)f2key(xv2)) << 14) | (unsigned)(16383 - xi2);
    ckey[lane] = k0; ckey[64 + lane] = k1; ckey[128 + lane] = k2;
    __syncthreads();
    int r0 = 0, r1 = 0, r2 = 0;
#pragma unroll 8
    for (int j = 0; j < 192; ++j) {
      unsigned long long kj = ckey[j];
      r0 += (kj > k0); r1 += (kj > k1); r2 += (kj > k2);
    }
    bool s0 = (r0 < K_TOP), s1 = (r1 < K_TOP), s2 = (r2 < K_TOP);
    unsigned long long m0 = __ballot(s0), m1 = __ballot(s1), m2 = __ballot(s2);
    unsigned long long lt = (1ull << lane) - 1ull;
    int base1 = __popcll(m0);
    int base2 = base1 + __popcll(m1);
    if (s0) { int p2 = __popcll(m0 & lt);          nzi[p2] = ri0; nzv[p2] = fmaxf(rv0, 0.0f); }
    if (s1) { int p2 = base1 + __popcll(m1 & lt);  nzi[p2] = ri1; nzv[p2] = fmaxf(rv1, 0.0f); }
    if (s2) { int p2 = base2 + __popcll(m2 & lt);  nzi[p2] = xi2; nzv[p2] = fmaxf(xv2, 0.0f); }
    __syncthreads();
    zidx = nzi[lane];
    zval = nzv[lane];
    zi[(size_t)row * 64 + lane] = zidx;
    zv[(size_t)row * 64 + lane] = zval;
    __syncthreads();
  }
}

// ---------- kernel 4: sparse decoder + recon loss ----------
__global__ __launch_bounds__(256) void sae_decode(
    const float* __restrict__ x, const float* __restrict__ W_dec,
    const float* __restrict__ b_dec, const int* __restrict__ zi,
    const float* __restrict__ zv, float* __restrict__ d_out) {
  const int row = blockIdx.x;
  const int tid = threadIdx.x;
  __shared__ int   si[64];
  __shared__ float sv[64];
  __shared__ float red[4];
  if (tid < 64) { si[tid] = zi[row * 64 + tid]; sv[tid] = zv[row * 64 + tid]; }
  __syncthreads();
  float a0 = b_dec[tid], a1 = b_dec[tid + 256], a2 = b_dec[tid + 512];
  for (int k = 0; k < 64; ++k) {
    float v = sv[k];
    if (v != 0.0f) {
      const float* w = W_dec + (size_t)si[k] * D_IN;
      a0 = fmaf(v, w[tid], a0);
      a1 = fmaf(v, w[tid + 256], a1);
      a2 = fmaf(v, w[tid + 512], a2);
    }
  }
  float* xhat = d_out + 1;
  size_t base = (size_t)row * D_IN;
  xhat[base + tid]       = a0;
  xhat[base + tid + 256] = a1;
  xhat[base + tid + 512] = a2;
  float d0 = a0 - x[base + tid];
  float d1 = a1 - x[base + tid + 256];
  float d2 = a2 - x[base + tid + 512];
  float s = d0 * d0 + d1 * d1 + d2 * d2;
  for (int o = 32; o > 0; o >>= 1) s += __shfl_down(s, o);
  if ((tid & 63) == 0) red[tid >> 6] = s;
  __syncthreads();
  if (tid == 0) {
    float tot = red[0] + red[1] + red[2] + red[3];
    atomicAdd(d_out, tot * (1.0f / (float)NROWS));
  }
}

// ---------- kernel 5: scatter z at t = T-1 into dense output ----------
__global__ void sae_scatter_last(const int* __restrict__ zi,
                                 const float* __restrict__ zv,
                                 float* __restrict__ d_out) {
  int i = blockIdx.x * blockDim.x + threadIdx.x;
  if (i >= B_SZ * 64) return;
  int b = i >> 6, k = i & 63;
  int row = b * T_LEN + (T_LEN - 1);
  float* zlast = d_out + 1 + (size_t)NROWS * D_IN;
  zlast[(size_t)b * D_SAE + zi[row * 64 + k]] = zv[row * 64 + k];
}

// ---------- launch ----------
extern "C" void kernel_launch(void* const* d_in, const int* in_sizes, int n_in,
                              void* d_out, int out_size, void* d_ws, size_t ws_size,
                              hipStream_t stream) {
  const float* x        = (const float*)d_in[0];
  const float* W_enc    = (const float*)d_in[1];
  const float* W_dec    = (const float*)d_in[2];
  const float* b_enc    = (const float*)d_in[3];
  const float* b_dec    = (const float*)d_in[4];
  const float* gate_raw = (const float*)d_in[5];
  float* out = (float*)d_out;

  char* ws = (char*)d_ws;
  float* pre   = (float*)ws;
  size_t off   = (size_t)NROWS * D_SAE * sizeof(float);   // 100,663,296
  int*   t128i = (int*)(ws + off);   off += (size_t)NROWS * 128 * sizeof(int);
  float* t128v = (float*)(ws + off); off += (size_t)NROWS * 128 * sizeof(float);
  int*   zidx  = (int*)(ws + off);   off += (size_t)NROWS * 64 * sizeof(int);
  float* zval  = (float*)(ws + off); off += (size_t)NROWS * 64 * sizeof(float);

  sae_init_out<<<(B_SZ * D_SAE + 255) / 256, 256, 0, stream>>>(out);
  dim3 g(D_SAE / BN, NROWS / BM);
  sae_gemm_enc<<<g, 256, 0, stream>>>(x, W_enc, b_enc, pre);
  sae_top128<<<NROWS, 256, 0, stream>>>(pre, t128i, t128v);
  sae_recur<<<B_SZ, 64, 0, stream>>>(pre, t128i, t128v, gate_raw, zidx, zval);
  sae_decode<<<NROWS, 256, 0, stream>>>(x, W_dec, b_dec, zidx, zval, out);
  sae_scatter_last<<<8, 256, 0, stream>>>(zidx, zval, out);
}

// Round 2
// 1068.650 us; speedup vs baseline: 1.4060x; 1.4060x over previous
//
#include <hip/hip_runtime.h>
#include <hip/hip_bf16.h>
#include <math.h>

#define D_IN   768
#define D_SAE  12288
#define T_LEN  64
#define K_TOP  64
#define B_SZ   32
#define NROWS  (B_SZ * T_LEN)   // 2048

// ---------- helpers ----------
__device__ __forceinline__ unsigned int f2key(float f) {
  unsigned int u = __float_as_uint(f);
  return (u & 0x80000000u) ? ~u : (u | 0x80000000u);
}

// ---------- kernel 0: init output (loss slot + z_last region) ----------
__global__ void sae_init_out(float* __restrict__ d_out) {
  int i = blockIdx.x * blockDim.x + threadIdx.x;
  if (i == 0) d_out[0] = 0.0f;
  if (i < B_SZ * D_SAE) d_out[1 + (size_t)NROWS * D_IN + i] = 0.0f;
}

// ---------- kernel 1: encoder GEMM, fp32 vector ----------
// C[m][n] = sum_k A[m][k]*B[k][n] + bias[n];  M=2048, N=12288, K=768
#define BM 128
#define BN 128
#define BK 16
__global__ __launch_bounds__(256) void sae_gemm_enc(
    const float* __restrict__ A, const float* __restrict__ Bm,
    const float* __restrict__ bias, float* __restrict__ C) {
  __shared__ float As[BK][BM];   // transposed A tile
  __shared__ float Bs[BK][BN];
  const int tid = threadIdx.x;
  const int bm = blockIdx.y * BM;
  const int bn = blockIdx.x * BN;
  const int tr  = (tid >> 4) << 3;        // 0..120, 8 contiguous rows
  const int tcq = (tid & 15) << 2;        // 0..60, cols tcq..+3 and 64+tcq..+3

  float acc[8][8];
#pragma unroll
  for (int i = 0; i < 8; ++i)
#pragma unroll
    for (int j = 0; j < 8; ++j) acc[i][j] = 0.0f;

  for (int k0 = 0; k0 < D_IN; k0 += BK) {
    __syncthreads();
#pragma unroll
    for (int l = 0; l < 2; ++l) {
      int idx = tid + (l << 8);           // 0..511
      int r = idx >> 2, c4 = idx & 3;
      const float4 av = *(const float4*)(A + (size_t)(bm + r) * D_IN + k0 + (c4 << 2));
      As[(c4 << 2) + 0][r] = av.x;
      As[(c4 << 2) + 1][r] = av.y;
      As[(c4 << 2) + 2][r] = av.z;
      As[(c4 << 2) + 3][r] = av.w;
      int rb = idx >> 5, cb = idx & 31;
      *(float4*)(&Bs[rb][cb << 2]) =
          *(const float4*)(Bm + (size_t)(k0 + rb) * D_SAE + bn + (cb << 2));
    }
    __syncthreads();
#pragma unroll
    for (int kk = 0; kk < BK; ++kk) {
      float a[8], b[8];
      *(float4*)&a[0] = *(const float4*)&As[kk][tr];
      *(float4*)&a[4] = *(const float4*)&As[kk][tr + 4];
      *(float4*)&b[0] = *(const float4*)&Bs[kk][tcq];
      *(float4*)&b[4] = *(const float4*)&Bs[kk][tcq + 64];
#pragma unroll
      for (int i = 0; i < 8; ++i)
#pragma unroll
        for (int j = 0; j < 8; ++j)
          acc[i][j] = fmaf(a[i], b[j], acc[i][j]);
    }
  }
  // epilogue with bias
#pragma unroll
  for (int i = 0; i < 8; ++i) {
    size_t base = (size_t)(bm + tr + i) * D_SAE + bn;
    float4 o0, o1;
    o0.x = acc[i][0] + bias[bn + tcq + 0];
    o0.y = acc[i][1] + bias[bn + tcq + 1];
    o0.z = acc[i][2] + bias[bn + tcq + 2];
    o0.w = acc[i][3] + bias[bn + tcq + 3];
    o1.x = acc[i][4] + bias[bn + 64 + tcq + 0];
    o1.y = acc[i][5] + bias[bn + 64 + tcq + 1];
    o1.z = acc[i][6] + bias[bn + 64 + tcq + 2];
    o1.w = acc[i][7] + bias[bn + 64 + tcq + 3];
    *(float4*)(C + base + tcq)      = o0;
    *(float4*)(C + base + 64 + tcq) = o1;
  }
}

// ---------- kernel 2: exact top-128 per row (radix select on sortable keys) ----------
__global__ __launch_bounds__(256) void sae_top128(
    const float* __restrict__ pre, int* __restrict__ t128i, float* __restrict__ t128v) {
  const int row = blockIdx.x;
  const int tid = threadIdx.x;
  __shared__ unsigned int keys[D_SAE];     // 48 KB
  __shared__ int hist[256];
  __shared__ int scn[256];
  __shared__ int sb, srem, scnt, scnt2;
  const float* p = pre + (size_t)row * D_SAE;
  for (int i = tid; i < D_SAE; i += 256) keys[i] = f2key(p[i]);

  const unsigned int PMASK[4] = {0u, 0xFF000000u, 0xFFFF0000u, 0xFFFFFF00u};
  unsigned int pacc = 0;      // accumulated threshold prefix (aligned in place)
  int remaining = 128;

  for (int round = 0; round < 4; ++round) {
    const int shift = 24 - 8 * round;
    hist[tid] = 0;
    __syncthreads();
    unsigned int pm = PMASK[round];
    for (int i = tid; i < D_SAE; i += 256) {
      unsigned int k = keys[i];
      if ((k & pm) == pacc) atomicAdd(&hist[(k >> shift) & 255], 1);
    }
    __syncthreads();
    // reverse inclusive scan: scn[b] = count(byte >= b)
    scn[tid] = hist[tid];
    __syncthreads();
    for (int d = 1; d < 256; d <<= 1) {
      int nv = scn[tid] + ((tid + d < 256) ? scn[tid + d] : 0);
      __syncthreads();
      scn[tid] = nv;
      __syncthreads();
    }
    int cum = scn[tid];
    int nxt = (tid < 255) ? scn[tid + 1] : 0;
    if (cum >= remaining && nxt < remaining) { sb = tid; srem = remaining - nxt; }
    __syncthreads();
    pacc |= ((unsigned int)sb) << shift;
    remaining = srem;
    __syncthreads();
  }
  // pacc = key of the 128th largest; remaining = # equal keys to take
  if (tid == 0) { scnt = 0; scnt2 = 0; }
  __syncthreads();
  const int ngt = 128 - remaining;
  for (int i = tid; i < D_SAE; i += 256) {
    unsigned int k = keys[i];
    if (k > pacc) {
      int pos = atomicAdd(&scnt, 1);
      t128i[row * 128 + pos] = i;
      t128v[row * 128 + pos] = p[i];
    } else if (k == pacc) {
      int pos = atomicAdd(&scnt2, 1);
      if (pos < remaining) {
        t128i[row * 128 + ngt + pos] = i;
        t128v[row * 128 + ngt + pos] = p[i];
      }
    }
  }
}

// ---------- kernel 3: recurrence — one wave per chain, LDS value maps ----------
// boost[idx]: gz value at prev-support positions (0 elsewhere). Replaces the
// 64-iteration shfl matching loop with one LDS gather per candidate.
// mark[idx]:  u16 timestamp of the step whose top-128 contains idx (matched test).
// sgate[idx]: sigmoid(gate_raw) precomputed once.
__global__ __launch_bounds__(64) void sae_recur(
    const float* __restrict__ pre, const int* __restrict__ t128i,
    const float* __restrict__ t128v, const float* __restrict__ gate_raw,
    int* __restrict__ zi, float* __restrict__ zv) {
  const int b = blockIdx.x;
  const int lane = threadIdx.x;
  __shared__ float boost[D_SAE];            // 48 KB
  __shared__ float sgate[D_SAE];            // 48 KB
  __shared__ unsigned short mark[D_SAE];    // 24 KB
  __shared__ unsigned long long ckey[192];
  __shared__ int   exi[64];
  __shared__ float exv[64];
  __shared__ int   nzi[64];
  __shared__ float nzv[64];

  for (int i = lane; i < D_SAE; i += 64) {
    boost[i] = 0.0f;
    mark[i] = 0xFFFFu;
    float g = gate_raw[i];
    sgate[i] = 1.0f / (1.0f + __expf(-g));
  }

  int   zidx = 0;
  float zval = 0.0f;
  // prefetch t=0 candidates
  int row0 = b * T_LEN;
  int   ri0 = t128i[row0 * 128 + lane];
  float rv0 = t128v[row0 * 128 + lane];
  int   ri1 = t128i[row0 * 128 + 64 + lane];
  float rv1 = t128v[row0 * 128 + 64 + lane];
  __syncthreads();

  const unsigned long long lt = (1ull << lane) - 1ull;

  for (int t = 0; t < T_LEN; ++t) {
    const int row = b * T_LEN + t;
    // issue state-dependent gather ASAP (value used only by extras)
    float pv = pre[(size_t)row * D_SAE + zidx];

    bool active = (zval > 0.0f);
    float gz = active ? zval * sgate[zidx] : 0.0f;
    if (active) boost[zidx] = gz;
    mark[ri0] = (unsigned short)t;
    mark[ri1] = (unsigned short)t;
    __syncthreads();
    rv0 += boost[ri0];
    rv1 += boost[ri1];
    bool matched = active && (mark[zidx] == (unsigned short)t);
    __syncthreads();                 // all map reads complete
    if (active) boost[zidx] = 0.0f;  // clear for next step

    // extras: prev-support positions not present in current top-128
    bool extra = active && !matched;
    unsigned long long em = __ballot(extra);
    int nExtra = __popcll(em);
    if (lane >= nExtra) { exi[lane] = D_SAE + lane; exv[lane] = -INFINITY; }
    if (extra) {
      int pos = __popcll(em & lt);
      exi[pos] = zidx;
      exv[pos] = pv + gz;
    }
    // own two candidate keys
    unsigned long long k0 =
        (((unsigned long long)f2key(rv0)) << 14) | (unsigned)(16383 - ri0);
    unsigned long long k1 =
        (((unsigned long long)f2key(rv1)) << 14) | (unsigned)(16383 - ri1);
    ckey[lane] = k0;
    ckey[64 + lane] = k1;
    __syncthreads();
    int   xi2 = exi[lane];
    float xv2 = exv[lane];
    unsigned long long k2 =
        (((unsigned long long)f2key(xv2)) << 14) | (unsigned)(16383 - xi2);
    ckey[128 + lane] = k2;
    __syncthreads();

    // prefetch next step's t128 (overlaps the rank loop)
    int   nri0 = ri0, nri1 = ri1;
    float nrv0 = rv0, nrv1 = rv1;
    if (t + 1 < T_LEN) {
      const int nrow = row + 1;
      nri0 = t128i[nrow * 128 + lane];
      nrv0 = t128v[nrow * 128 + lane];
      nri1 = t128i[nrow * 128 + 64 + lane];
      nrv1 = t128v[nrow * 128 + 64 + lane];
    }

    // exact counting rank over 192 candidates (keys all distinct)
    int r0 = 0, r1 = 0, r2 = 0;
#pragma unroll 16
    for (int j = 0; j < 192; ++j) {
      unsigned long long kj = ckey[j];
      r0 += (kj > k0);
      r1 += (kj > k1);
      r2 += (kj > k2);
    }
    bool s0 = (r0 < K_TOP), s1 = (r1 < K_TOP), s2 = (r2 < K_TOP);
    unsigned long long m0 = __ballot(s0), m1 = __ballot(s1), m2 = __ballot(s2);
    int base1 = __popcll(m0);
    int base2 = base1 + __popcll(m1);
    if (s0) { int p2 = __popcll(m0 & lt);          nzi[p2] = ri0; nzv[p2] = fmaxf(rv0, 0.0f); }
    if (s1) { int p2 = base1 + __popcll(m1 & lt);  nzi[p2] = ri1; nzv[p2] = fmaxf(rv1, 0.0f); }
    if (s2) { int p2 = base2 + __popcll(m2 & lt);  nzi[p2] = xi2; nzv[p2] = fmaxf(xv2, 0.0f); }
    __syncthreads();
    zidx = nzi[lane];
    zval = nzv[lane];
    zi[(size_t)row * 64 + lane] = zidx;
    zv[(size_t)row * 64 + lane] = zval;
    __syncthreads();

    ri0 = nri0; rv0 = nrv0; ri1 = nri1; rv1 = nrv1;
  }
}

// ---------- kernel 4: sparse decoder + recon loss ----------
__global__ __launch_bounds__(256) void sae_decode(
    const float* __restrict__ x, const float* __restrict__ W_dec,
    const float* __restrict__ b_dec, const int* __restrict__ zi,
    const float* __restrict__ zv, float* __restrict__ d_out) {
  const int row = blockIdx.x;
  const int tid = threadIdx.x;
  __shared__ int   si[64];
  __shared__ float sv[64];
  __shared__ float red[4];
  if (tid < 64) { si[tid] = zi[row * 64 + tid]; sv[tid] = zv[row * 64 + tid]; }
  __syncthreads();
  float a0 = b_dec[tid], a1 = b_dec[tid + 256], a2 = b_dec[tid + 512];
  for (int k = 0; k < 64; ++k) {
    float v = sv[k];
    if (v != 0.0f) {
      const float* w = W_dec + (size_t)si[k] * D_IN;
      a0 = fmaf(v, w[tid], a0);
      a1 = fmaf(v, w[tid + 256], a1);
      a2 = fmaf(v, w[tid + 512], a2);
    }
  }
  float* xhat = d_out + 1;
  size_t base = (size_t)row * D_IN;
  xhat[base + tid]       = a0;
  xhat[base + tid + 256] = a1;
  xhat[base + tid + 512] = a2;
  float d0 = a0 - x[base + tid];
  float d1 = a1 - x[base + tid + 256];
  float d2 = a2 - x[base + tid + 512];
  float s = d0 * d0 + d1 * d1 + d2 * d2;
  for (int o = 32; o > 0; o >>= 1) s += __shfl_down(s, o);
  if ((tid & 63) == 0) red[tid >> 6] = s;
  __syncthreads();
  if (tid == 0) {
    float tot = red[0] + red[1] + red[2] + red[3];
    atomicAdd(d_out, tot * (1.0f / (float)NROWS));
  }
}

// ---------- kernel 5: scatter z at t = T-1 into dense output ----------
__global__ void sae_scatter_last(const int* __restrict__ zi,
                                 const float* __restrict__ zv,
                                 float* __restrict__ d_out) {
  int i = blockIdx.x * blockDim.x + threadIdx.x;
  if (i >= B_SZ * 64) return;
  int b = i >> 6, k = i & 63;
  int row = b * T_LEN + (T_LEN - 1);
  float* zlast = d_out + 1 + (size_t)NROWS * D_IN;
  zlast[(size_t)b * D_SAE + zi[row * 64 + k]] = zv[row * 64 + k];
}

// ---------- launch ----------
extern "C" void kernel_launch(void* const* d_in, const int* in_sizes, int n_in,
                              void* d_out, int out_size, void* d_ws, size_t ws_size,
                              hipStream_t stream) {
  const float* x        = (const float*)d_in[0];
  const float* W_enc    = (const float*)d_in[1];
  const float* W_dec    = (const float*)d_in[2];
  const float* b_enc    = (const float*)d_in[3];
  const float* b_dec    = (const float*)d_in[4];
  const float* gate_raw = (const float*)d_in[5];
  float* out = (float*)d_out;

  char* ws = (char*)d_ws;
  float* pre   = (float*)ws;
  size_t off   = (size_t)NROWS * D_SAE * sizeof(float);   // 100,663,296
  int*   t128i = (int*)(ws + off);   off += (size_t)NROWS * 128 * sizeof(int);
  float* t128v = (float*)(ws + off); off += (size_t)NROWS * 128 * sizeof(float);
  int*   zidx  = (int*)(ws + off);   off += (size_t)NROWS * 64 * sizeof(int);
  float* zval  = (float*)(ws + off); off += (size_t)NROWS * 64 * sizeof(float);

  sae_init_out<<<(B_SZ * D_SAE + 255) / 256, 256, 0, stream>>>(out);
  dim3 g(D_SAE / BN, NROWS / BM);
  sae_gemm_enc<<<g, 256, 0, stream>>>(x, W_enc, b_enc, pre);
  sae_top128<<<NROWS, 256, 0, stream>>>(pre, t128i, t128v);
  sae_recur<<<B_SZ, 64, 0, stream>>>(pre, t128i, t128v, gate_raw, zidx, zval);
  sae_decode<<<NROWS, 256, 0, stream>>>(x, W_dec, b_dec, zidx, zval, out);
  sae_scatter_last<<<8, 256, 0, stream>>>(zidx, zval, out);
}

// Round 3
// 631.028 us; speedup vs baseline: 2.3810x; 1.6935x over previous
//
#include <hip/hip_runtime.h>
#include <hip/hip_bf16.h>
#include <math.h>

#define D_IN   768
#define D_SAE  12288
#define T_LEN  64
#define K_TOP  64
#define B_SZ   32
#define NROWS  (B_SZ * T_LEN)   // 2048
#define KT     24               // 768/32 k-tiles

typedef _Float16 h8 __attribute__((ext_vector_type(8)));
typedef float f4 __attribute__((ext_vector_type(4)));

// ---------- helpers ----------
__device__ __forceinline__ unsigned int f2key(float f) {
  unsigned int u = __float_as_uint(f);
  return (u & 0x80000000u) ? ~u : (u | 0x80000000u);
}

#define GLOAD16(g, l)                                                        \
  __builtin_amdgcn_global_load_lds(                                          \
      (const __attribute__((address_space(1))) unsigned int*)(g),            \
      (__attribute__((address_space(3))) unsigned int*)(l), 16, 0, 0)

// ---------- kernel 0: init output (loss slot + z_last region) ----------
__global__ void sae_init_out(float* __restrict__ d_out) {
  int i = blockIdx.x * blockDim.x + threadIdx.x;
  if (i == 0) d_out[0] = 0.0f;
  if (i < B_SZ * D_SAE) d_out[1 + (size_t)NROWS * D_IN + i] = 0.0f;
}

// ---------- split kernels: fp32 -> (hi, lo*4096) fp16, MFMA-fragment packed ----------
// A packed tile (tm, tk): lane l holds A[tm*16 + (l&15)][tk*32 + (l>>4)*8 + j], j=0..7
__global__ __launch_bounds__(256) void sae_split_A(
    const float* __restrict__ A, _Float16* __restrict__ Ah, _Float16* __restrict__ Al) {
  int g = blockIdx.x * 256 + threadIdx.x;          // < 128*24*64 = 196608
  int tile = g >> 6, l = g & 63;
  int tm = tile / KT, tk = tile - tm * KT;
  int m = (tm << 4) + (l & 15);
  int k = (tk << 5) + ((l >> 4) << 3);
  const float* src = A + (size_t)m * D_IN + k;
  float4 v0 = *(const float4*)src;
  float4 v1 = *(const float4*)(src + 4);
  float f[8] = {v0.x, v0.y, v0.z, v0.w, v1.x, v1.y, v1.z, v1.w};
  h8 hi, lo;
#pragma unroll
  for (int j = 0; j < 8; ++j) {
    _Float16 h = (_Float16)f[j];
    hi[j] = h;
    lo[j] = (_Float16)((f[j] - (float)h) * 4096.0f);
  }
  *(h8*)(Ah + (size_t)g * 8) = hi;
  *(h8*)(Al + (size_t)g * 8) = lo;
}

// B packed tile (tn, tk): lane l holds B[tk*32 + (l>>4)*8 + j][tn*16 + (l&15)]
__global__ __launch_bounds__(256) void sae_split_B(
    const float* __restrict__ B, _Float16* __restrict__ Bh, _Float16* __restrict__ Bl) {
  int g = blockIdx.x * 256 + threadIdx.x;          // < 768*24*64 = 1179648
  int tile = g >> 6, l = g & 63;
  int tn = tile / KT, tk = tile - tn * KT;
  int n = (tn << 4) + (l & 15);
  int k = (tk << 5) + ((l >> 4) << 3);
  h8 hi, lo;
#pragma unroll
  for (int j = 0; j < 8; ++j) {
    float f = B[(size_t)(k + j) * D_SAE + n];
    _Float16 h = (_Float16)f;
    hi[j] = h;
    lo[j] = (_Float16)((f - (float)h) * 4096.0f);
  }
  *(h8*)(Bh + (size_t)g * 8) = hi;
  *(h8*)(Bl + (size_t)g * 8) = lo;
}

// ---------- kernel 1: encoder GEMM via fp16-split MFMA ----------
// tile 128x128, 8 waves (2m x 4n), each wave 64x32 output, BK=32, LDS dbuf
__global__ __launch_bounds__(512) void sae_gemm_mfma(
    const _Float16* __restrict__ Ah, const _Float16* __restrict__ Al,
    const _Float16* __restrict__ Bh, const _Float16* __restrict__ Bl,
    const float* __restrict__ bias, float* __restrict__ C) {
  __shared__ _Float16 lds[2][16384];               // 2 x 32 KB
  const int tid = threadIdx.x;
  const int w = tid >> 6, lane = tid & 63;
  const int wm = w >> 2, wn = w & 3;
  const int bmT = blockIdx.y * 8;                  // m-frag-tile base
  const int bnT = blockIdx.x * 8;                  // n-frag-tile base

  f4 accm[4][2], accc[4][2];
#pragma unroll
  for (int i = 0; i < 4; ++i)
#pragma unroll
    for (int j = 0; j < 2; ++j) {
      accm[i][j] = (f4){0.f, 0.f, 0.f, 0.f};
      accc[i][j] = (f4){0.f, 0.f, 0.f, 0.f};
    }

#define STAGE(buf, tk)                                                         \
  {                                                                            \
    const _Float16* s0 = Ah + ((size_t)(bmT + w) * KT + (tk)) * 512;           \
    const _Float16* s1 = Al + ((size_t)(bmT + w) * KT + (tk)) * 512;           \
    const _Float16* s2 = Bh + ((size_t)(bnT + w) * KT + (tk)) * 512;           \
    const _Float16* s3 = Bl + ((size_t)(bnT + w) * KT + (tk)) * 512;           \
    GLOAD16(s0 + lane * 8, &lds[buf][(0 * 8 + w) * 512]);                      \
    GLOAD16(s1 + lane * 8, &lds[buf][(1 * 8 + w) * 512]);                      \
    GLOAD16(s2 + lane * 8, &lds[buf][(2 * 8 + w) * 512]);                      \
    GLOAD16(s3 + lane * 8, &lds[buf][(3 * 8 + w) * 512]);                      \
  }

  STAGE(0, 0);
  __syncthreads();
  for (int tk = 0; tk < KT; ++tk) {
    int buf = tk & 1;
    if (tk + 1 < KT) STAGE(buf ^ 1, tk + 1);
    h8 ah[4], al4[4], bh2[2], bl2[2];
#pragma unroll
    for (int i = 0; i < 4; ++i) {
      ah[i]  = *(const h8*)&lds[buf][(wm * 4 + i) * 512 + lane * 8];
      al4[i] = *(const h8*)&lds[buf][4096 + (wm * 4 + i) * 512 + lane * 8];
    }
#pragma unroll
    for (int j = 0; j < 2; ++j) {
      bh2[j] = *(const h8*)&lds[buf][8192 + (wn * 2 + j) * 512 + lane * 8];
      bl2[j] = *(const h8*)&lds[buf][12288 + (wn * 2 + j) * 512 + lane * 8];
    }
#pragma unroll
    for (int i = 0; i < 4; ++i)
#pragma unroll
      for (int j = 0; j < 2; ++j) {
        accm[i][j] = __builtin_amdgcn_mfma_f32_16x16x32_f16(ah[i], bh2[j], accm[i][j], 0, 0, 0);
        accc[i][j] = __builtin_amdgcn_mfma_f32_16x16x32_f16(ah[i], bl2[j], accc[i][j], 0, 0, 0);
        accc[i][j] = __builtin_amdgcn_mfma_f32_16x16x32_f16(al4[i], bh2[j], accc[i][j], 0, 0, 0);
      }
    __syncthreads();
  }
#undef STAGE

  const float kLo = 1.0f / 4096.0f;
  const int colb = blockIdx.x * 128 + wn * 32;
  const int rowb = blockIdx.y * 128 + wm * 64;
#pragma unroll
  for (int j = 0; j < 2; ++j) {
    int col = colb + j * 16 + (lane & 15);
    float bv = bias[col];
#pragma unroll
    for (int i = 0; i < 4; ++i) {
      int row = rowb + i * 16 + ((lane >> 4) << 2);
#pragma unroll
      for (int r = 0; r < 4; ++r)
        C[(size_t)(row + r) * D_SAE + col] = accm[i][j][r] + accc[i][j][r] * kLo + bv;
    }
  }
}

// ---------- kernel 2: exact top-128 per row (radix select) ----------
__global__ __launch_bounds__(256) void sae_top128(
    const float* __restrict__ pre, int* __restrict__ t128i, float* __restrict__ t128v) {
  const int row = blockIdx.x;
  const int tid = threadIdx.x;
  __shared__ unsigned int keys[D_SAE];
  __shared__ int hist[256];
  __shared__ int scn[256];
  __shared__ int sb, srem, scnt, scnt2;
  const float* p = pre + (size_t)row * D_SAE;
  for (int i = tid; i < D_SAE; i += 256) keys[i] = f2key(p[i]);

  const unsigned int PMASK[4] = {0u, 0xFF000000u, 0xFFFF0000u, 0xFFFFFF00u};
  unsigned int pacc = 0;
  int remaining = 128;

  for (int round = 0; round < 4; ++round) {
    const int shift = 24 - 8 * round;
    hist[tid] = 0;
    __syncthreads();
    unsigned int pm = PMASK[round];
    for (int i = tid; i < D_SAE; i += 256) {
      unsigned int k = keys[i];
      if ((k & pm) == pacc) atomicAdd(&hist[(k >> shift) & 255], 1);
    }
    __syncthreads();
    scn[tid] = hist[tid];
    __syncthreads();
    for (int d = 1; d < 256; d <<= 1) {
      int nv = scn[tid] + ((tid + d < 256) ? scn[tid + d] : 0);
      __syncthreads();
      scn[tid] = nv;
      __syncthreads();
    }
    int cum = scn[tid];
    int nxt = (tid < 255) ? scn[tid + 1] : 0;
    if (cum >= remaining && nxt < remaining) { sb = tid; srem = remaining - nxt; }
    __syncthreads();
    pacc |= ((unsigned int)sb) << shift;
    remaining = srem;
    __syncthreads();
  }
  if (tid == 0) { scnt = 0; scnt2 = 0; }
  __syncthreads();
  const int ngt = 128 - remaining;
  for (int i = tid; i < D_SAE; i += 256) {
    unsigned int k = keys[i];
    if (k > pacc) {
      int pos = atomicAdd(&scnt, 1);
      t128i[row * 128 + pos] = i;
      t128v[row * 128 + pos] = p[i];
    } else if (k == pacc) {
      int pos = atomicAdd(&scnt2, 1);
      if (pos < remaining) {
        t128i[row * 128 + ngt + pos] = i;
        t128v[row * 128 + ngt + pos] = p[i];
      }
    }
  }
}

// ---------- kernel 3: recurrence — 4 waves per chain ----------
__global__ __launch_bounds__(256) void sae_recur(
    const float* __restrict__ pre, const int* __restrict__ t128i,
    const float* __restrict__ t128v, const float* __restrict__ gate_raw,
    int* __restrict__ zi, float* __restrict__ zv) {
  const int b = blockIdx.x;
  const int tid = threadIdx.x;
  const int lane = tid & 63;
  const int w = tid >> 6;
  __shared__ float boost[D_SAE];            // 48 KB
  __shared__ float sgate[D_SAE];            // 48 KB
  __shared__ unsigned short mark[D_SAE];    // 24 KB
  __shared__ unsigned long long ckey[192];
  __shared__ int   szi[64];
  __shared__ float szv[64];
  __shared__ int   exi[64];
  __shared__ float exv[64];
  __shared__ int   wcnt[4];
  __shared__ unsigned short zhi[T_LEN * 64];  // 8 KB
  __shared__ float zhv[T_LEN * 64];           // 16 KB

  for (int i = tid; i < D_SAE; i += 256) {
    boost[i] = 0.0f;
    mark[i] = 0xFFFFu;
    sgate[i] = 1.0f / (1.0f + __expf(-gate_raw[i]));
  }
  if (tid < 64) { szv[tid] = 0.0f; szi[tid] = 0; }
  __syncthreads();

  int   zidx = 0; float zval = 0.0f; float pv = 0.0f;   // wave-0 state
  int   ri = 0;   float rv = 0.0f;                      // candidate (tid<128)
  if (tid < 128) {
    ri = t128i[(size_t)(b * T_LEN) * 128 + tid];
    rv = t128v[(size_t)(b * T_LEN) * 128 + tid];
  }
  const unsigned long long lt = (1ull << lane) - 1ull;

  for (int t = 0; t < T_LEN; ++t) {
    const int row = b * T_LEN + t;
    // P0: state scatter + marks
    bool active = false; float gz = 0.0f;
    if (w == 0) {
      active = (zval > 0.0f);
      gz = active ? zval * sgate[zidx] : 0.0f;
      if (active) boost[zidx] = gz;
    }
    if (tid < 128) mark[ri] = (unsigned short)t;
    __syncthreads();                                   // B1
    // P1: boost gather; matched; extras
    int myi = ri; float myv = rv;
    if (tid < 128) myv = rv + boost[ri];
    if (w == 0) {
      bool matched = active && (mark[zidx] == (unsigned short)t);
      bool extra = active && !matched;
      unsigned long long em = __ballot(extra);
      int ne = __popcll(em);
      if (extra) {
        int pos = __popcll(em & lt);
        exi[pos] = zidx; exv[pos] = pv + gz;
      }
      if (lane >= ne) { exi[lane] = D_SAE + lane; exv[lane] = -INFINITY; }
    }
    __syncthreads();                                   // B2
    // P2: clear boost; build keys
    if (w == 0 && active) boost[zidx] = 0.0f;
    unsigned long long kc = 0;
    if (tid < 128) {
      kc = (((unsigned long long)f2key(myv)) << 14) | (unsigned)(16383 - myi);
      ckey[tid] = kc;
    } else if (tid < 192) {
      myi = exi[tid - 128]; myv = exv[tid - 128];
      kc = (((unsigned long long)f2key(myv)) << 14) | (unsigned)(16383 - myi);
      ckey[tid] = kc;
    }
    __syncthreads();                                   // B3
    // P3: prefetch next t128 (hidden under rank) + counting rank
    int nri = ri; float nrv = rv;
    if (t + 1 < T_LEN && tid < 128) {
      nri = t128i[(size_t)(row + 1) * 128 + tid];
      nrv = t128v[(size_t)(row + 1) * 128 + tid];
    }
    int r = 0;
    if (tid < 192) {
#pragma unroll 16
      for (int j = 0; j < 192; ++j) r += (ckey[j] > kc);
    }
    bool sel = (tid < 192) && (r < K_TOP);
    unsigned long long m = __ballot(sel);
    if (tid < 192 && lane == 0) wcnt[w] = __popcll(m);
    __syncthreads();                                   // B4
    // P4: compaction into new state
    if (sel) {
      int base = 0;
#pragma unroll
      for (int ww = 0; ww < 3; ++ww) base += (ww < w) ? wcnt[ww] : 0;
      int pos = base + __popcll(m & lt);
      szi[pos] = myi;
      szv[pos] = fmaxf(myv, 0.0f);
    }
    __syncthreads();                                   // B5
    // P5: wave 0 records + loads new state + next-step pre gather
    if (w == 0) {
      zidx = szi[lane];
      zval = szv[lane];
      zhi[t * 64 + lane] = (unsigned short)zidx;
      zhv[t * 64 + lane] = zval;
      if (t + 1 < T_LEN) pv = pre[(size_t)(row + 1) * D_SAE + zidx];
    }
    ri = nri; rv = nrv;
  }
  __syncthreads();
  // dump history
  for (int i = tid; i < T_LEN * 64; i += 256) {
    size_t rr = (size_t)(b * T_LEN + (i >> 6));
    zi[rr * 64 + (i & 63)] = (int)zhi[i];
    zv[rr * 64 + (i & 63)] = zhv[i];
  }
}

// ---------- kernel 4: sparse decoder + recon loss ----------
__global__ __launch_bounds__(256) void sae_decode(
    const float* __restrict__ x, const float* __restrict__ W_dec,
    const float* __restrict__ b_dec, const int* __restrict__ zi,
    const float* __restrict__ zv, float* __restrict__ d_out) {
  const int row = blockIdx.x;
  const int tid = threadIdx.x;
  __shared__ int   si[64];
  __shared__ float sv[64];
  __shared__ float red[4];
  if (tid < 64) { si[tid] = zi[row * 64 + tid]; sv[tid] = zv[row * 64 + tid]; }
  __syncthreads();
  float a0 = b_dec[tid], a1 = b_dec[tid + 256], a2 = b_dec[tid + 512];
  for (int k = 0; k < 64; ++k) {
    float v = sv[k];
    if (v != 0.0f) {
      const float* wp = W_dec + (size_t)si[k] * D_IN;
      a0 = fmaf(v, wp[tid], a0);
      a1 = fmaf(v, wp[tid + 256], a1);
      a2 = fmaf(v, wp[tid + 512], a2);
    }
  }
  float* xhat = d_out + 1;
  size_t base = (size_t)row * D_IN;
  xhat[base + tid]       = a0;
  xhat[base + tid + 256] = a1;
  xhat[base + tid + 512] = a2;
  float d0 = a0 - x[base + tid];
  float d1 = a1 - x[base + tid + 256];
  float d2 = a2 - x[base + tid + 512];
  float s = d0 * d0 + d1 * d1 + d2 * d2;
  for (int o = 32; o > 0; o >>= 1) s += __shfl_down(s, o);
  if ((tid & 63) == 0) red[tid >> 6] = s;
  __syncthreads();
  if (tid == 0) {
    float tot = red[0] + red[1] + red[2] + red[3];
    atomicAdd(d_out, tot * (1.0f / (float)NROWS));
  }
}

// ---------- kernel 5: scatter z at t = T-1 ----------
__global__ void sae_scatter_last(const int* __restrict__ zi,
                                 const float* __restrict__ zv,
                                 float* __restrict__ d_out) {
  int i = blockIdx.x * blockDim.x + threadIdx.x;
  if (i >= B_SZ * 64) return;
  int b = i >> 6, k = i & 63;
  int row = b * T_LEN + (T_LEN - 1);
  float* zlast = d_out + 1 + (size_t)NROWS * D_IN;
  zlast[(size_t)b * D_SAE + zi[row * 64 + k]] = zv[row * 64 + k];
}

// ---------- launch ----------
extern "C" void kernel_launch(void* const* d_in, const int* in_sizes, int n_in,
                              void* d_out, int out_size, void* d_ws, size_t ws_size,
                              hipStream_t stream) {
  const float* x        = (const float*)d_in[0];
  const float* W_enc    = (const float*)d_in[1];
  const float* W_dec    = (const float*)d_in[2];
  const float* b_enc    = (const float*)d_in[3];
  const float* b_dec    = (const float*)d_in[4];
  const float* gate_raw = (const float*)d_in[5];
  float* out = (float*)d_out;

  char* ws = (char*)d_ws;
  size_t off = 0;
  float* pre   = (float*)(ws + off); off += (size_t)NROWS * D_SAE * sizeof(float);
  int*   t128i = (int*)(ws + off);   off += (size_t)NROWS * 128 * sizeof(int);
  float* t128v = (float*)(ws + off); off += (size_t)NROWS * 128 * sizeof(float);
  int*   zidx  = (int*)(ws + off);   off += (size_t)NROWS * 64 * sizeof(int);
  float* zval  = (float*)(ws + off); off += (size_t)NROWS * 64 * sizeof(float);
  _Float16* Ah = (_Float16*)(ws + off); off += (size_t)NROWS * D_IN * sizeof(_Float16);
  _Float16* Al = (_Float16*)(ws + off); off += (size_t)NROWS * D_IN * sizeof(_Float16);
  _Float16* Bh = (_Float16*)(ws + off); off += (size_t)D_IN * D_SAE * sizeof(_Float16);
  _Float16* Bl = (_Float16*)(ws + off); off += (size_t)D_IN * D_SAE * sizeof(_Float16);

  sae_init_out<<<(B_SZ * D_SAE + 255) / 256, 256, 0, stream>>>(out);
  sae_split_A<<<(NROWS * D_IN / 8 + 255) / 256, 256, 0, stream>>>(x, Ah, Al);
  sae_split_B<<<(D_IN * D_SAE / 8 + 255) / 256, 256, 0, stream>>>(W_enc, Bh, Bl);
  sae_gemm_mfma<<<dim3(D_SAE / 128, NROWS / 128), 512, 0, stream>>>(
      Ah, Al, Bh, Bl, b_enc, pre);
  sae_top128<<<NROWS, 256, 0, stream>>>(pre, t128i, t128v);
  sae_recur<<<B_SZ, 256, 0, stream>>>(pre, t128i, t128v, gate_raw, zidx, zval);
  sae_decode<<<NROWS, 256, 0, stream>>>(x, W_dec, b_dec, zidx, zval, out);
  sae_scatter_last<<<8, 256, 0, stream>>>(zidx, zval, out);
}